// Round 1
// baseline (377.782 us; speedup 1.0000x reference)
//
#include <hip/hip_runtime.h>
#include <math.h>

// MultiHeadBigBirdAttention: B=2, S=2048, E=1024, H=8, DH=128
// Pipeline (bf16 MFMA 16x16x32):
//   1. prep: fused {q,k,v fp32->bf16} + {W* fp32 [K][N] -> bf16 W^T [N][K]}
//   2. gemm_k<0> (grid.z=3): projections -> Qh/Kh [B,H,S,DH], Vt [B,H,DH,S]
//   3. flash_k: static-max flash -> ctx bf16
//   4. gemm_k<1>: ctx @ Wo^T + bo -> d_out fp32
//
// MFMA layouts (verified learn_hip m89/m91/m120):
//   C/D: col = lane&15, row = (lane>>4)*4 + reg
//   A:   m   = lane&15, k   = (lane>>4)*8 + j
//   B:   n   = lane&15, k   = (lane>>4)*8 + j
//
// R9 (this round): flash_k reads K/V fragments DIRECTLY from global.
// Rationale: per-XCD K/V working set is ~2 heads x 1MB = 2MB < 4MB L2
// (blocks with equal bh land on one XCD: n0 mod 8 == bh mod 8), and LDS
// staging had only 4x reuse per 16KB tile. Dropping it removes every
// __syncthreads in the k-loop and cuts LDS 74KB -> 11KB (occupancy was
// the limiter: 2 blocks/CU, Occupancy 12%, MfmaUtil 13%). Ps stride
// 80 -> 88 halves the ds_write_b16 scatter conflict (8-way -> 4-way).

typedef __bf16 bf16_t;
typedef __bf16 bf16x8 __attribute__((ext_vector_type(8)));
typedef float f32x4 __attribute__((ext_vector_type(4)));

#define MFMA16(a, b, c) __builtin_amdgcn_mfma_f32_16x16x32_bf16(a, b, c, 0, 0, 0)

// ---------------------------------------------------------------------------
// prep: blocks 0..6143 convert q/k/v fp32->bf16 (8 elems/thread);
//       blocks 6144..10239 transpose the 4 weight matrices to bf16 W^T.
// ---------------------------------------------------------------------------
__global__ __launch_bounds__(256) void prep(const float* q, const float* k,
                                            const float* v, bf16_t* qb,
                                            bf16_t* kb, bf16_t* vb,
                                            const float* W0, const float* W1,
                                            const float* W2, const float* W3,
                                            bf16_t* Wt) {
  const int bid = blockIdx.x, tid = threadIdx.x;
  if (bid < 6144) {
    const int z = bid >> 11, chunk = bid & 2047;
    const float* x = (z == 0) ? q : (z == 1) ? k : v;
    bf16_t* y = (z == 0) ? qb : (z == 1) ? kb : vb;
    size_t i = ((size_t)chunk * 256 + tid) * 8;
    float4 a = *(const float4*)(x + i);
    float4 b = *(const float4*)(x + i + 4);
    bf16x8 o = {(bf16_t)a.x, (bf16_t)a.y, (bf16_t)a.z, (bf16_t)a.w,
                (bf16_t)b.x, (bf16_t)b.y, (bf16_t)b.z, (bf16_t)b.w};
    *(bf16x8*)(y + i) = o;
  } else {
    __shared__ float t[32][33];
    const int b2 = bid - 6144;
    const int wz = b2 >> 10, t2 = b2 & 1023;
    const float* W = (wz == 0) ? W0 : (wz == 1) ? W1 : (wz == 2) ? W2 : W3;
    bf16_t* o = Wt + (size_t)wz * 1024 * 1024;
    const int n0 = (t2 & 31) * 32, k0 = (t2 >> 5) * 32;
    const int tx = tid & 31, ty = tid >> 5;
#pragma unroll
    for (int i = 0; i < 4; i++)
      t[ty + 8 * i][tx] = W[(size_t)(k0 + ty + 8 * i) * 1024 + n0 + tx];
    __syncthreads();
#pragma unroll
    for (int i = 0; i < 4; i++)
      o[(size_t)(n0 + ty + 8 * i) * 1024 + k0 + tx] = (bf16_t)t[tx][ty + 8 * i];
  }
}

// ---------------------------------------------------------------------------
// GEMM 128x128 tile, BK=64, LDS double-buffered, register-staged pipeline.
// LDS [128][64] per buffer; chunk (8 elems) swizzle: slot(r,c) holds chunk
// c^(r&7) (R6-proven conflict-free for the fragment reads).
// Staging: thread -> row r2=tid>>1, chunks cb..cb+3 (cb=(tid&1)*4).
// ---------------------------------------------------------------------------
template <int MODE>
__global__ __launch_bounds__(256) void gemm_k(
    const bf16_t* qb, const bf16_t* kb, const bf16_t* vb, const bf16_t* Wt,
    const float* b0, const float* b1, const float* b2, bf16_t* Qh, bf16_t* Kh,
    bf16_t* Vt, float* Of32) {
  __shared__ bf16_t As[2][128 * 64];
  __shared__ bf16_t Bs[2][128 * 64];
  const int tid = threadIdx.x, w = tid >> 6, lane = tid & 63;
  const int bm = blockIdx.y, bn = blockIdx.x;
  const int wr = w >> 1, wc = w & 1, q4 = lane >> 4, lo = lane & 15;
  const int z = (MODE == 0) ? blockIdx.z : 3;
  const bf16_t* A = (MODE == 1) ? qb : (z == 0) ? qb : (z == 1) ? kb : vb;
  const bf16_t* Bt = Wt + (size_t)z * 1024 * 1024;
  const float* bias = (MODE == 1) ? b0 : (z == 0) ? b0 : (z == 1) ? b1 : b2;

  f32x4 acc[4][4];
#pragma unroll
  for (int m = 0; m < 4; m++)
#pragma unroll
    for (int n = 0; n < 4; n++) acc[m][n] = (f32x4){0.f, 0.f, 0.f, 0.f};

  const int r2 = tid >> 1;         // 0..127
  const int cb = (tid & 1) * 4;    // chunk base 0 / 4
  const bf16_t* Arow = A + (size_t)(bm * 128 + r2) * 1024;
  const bf16_t* Brow = Bt + (size_t)(bn * 128 + r2) * 1024;

  bf16x8 ar[4], br[4];
  auto loadAB = [&](int k0) {
#pragma unroll
    for (int i = 0; i < 4; i++) {
      ar[i] = *(const bf16x8*)(Arow + k0 + (cb + i) * 8);
      br[i] = *(const bf16x8*)(Brow + k0 + (cb + i) * 8);
    }
  };

  loadAB(0);
  for (int k = 0; k < 16; k++) {
    const int cur = k & 1;
    // deposit tile k (waits only on its own global loads)
#pragma unroll
    for (int i = 0; i < 4; i++) {
      *(bf16x8*)&As[cur][r2 * 64 + (((cb + i) ^ (r2 & 7)) * 8)] = ar[i];
      *(bf16x8*)&Bs[cur][r2 * 64 + (((cb + i) ^ (r2 & 7)) * 8)] = br[i];
    }
    // prefetch tile k+1 into private regs (in flight through barrier+compute)
    if (k < 15) loadAB((k + 1) * 64);
    __syncthreads();

#pragma unroll
    for (int kc = 0; kc < 2; kc++) {
      bf16x8 af[4], bfr[4];
#pragma unroll
      for (int m = 0; m < 4; m++) {
        int rr = wr * 64 + m * 16 + lo;
        af[m] = *(const bf16x8*)&As[cur][rr * 64 + (((kc * 4 + q4) ^ (rr & 7)) * 8)];
      }
#pragma unroll
      for (int n = 0; n < 4; n++) {
        int rr = wc * 64 + n * 16 + lo;
        bfr[n] = *(const bf16x8*)&Bs[cur][rr * 64 + (((kc * 4 + q4) ^ (rr & 7)) * 8)];
      }
#pragma unroll
      for (int m = 0; m < 4; m++)
#pragma unroll
        for (int n = 0; n < 4; n++)
          acc[m][n] = MFMA16(af[m], bfr[n], acc[m][n]);
    }
    // no trailing barrier: dbuf + top-of-iter deposit make it safe
  }

#pragma unroll
  for (int m = 0; m < 4; m++) {
#pragma unroll
    for (int n = 0; n < 4; n++) {
      int rowg0 = bm * 128 + wr * 64 + m * 16 + q4 * 4;
      int colg = bn * 128 + wc * 64 + n * 16 + lo;
      float bv = bias[colg];
#pragma unroll
      for (int rg = 0; rg < 4; rg++) {
        float val = acc[m][n][rg] + bv;
        int row = rowg0 + rg;
        if (MODE == 1) {
          Of32[(size_t)row * 1024 + colg] = val;
        } else {
          int b = row >> 11, s = row & 2047;  // S=2048
          int h = colg >> 7, d = colg & 127;  // DH=128
          if (z == 0)
            Qh[(((size_t)(b * 8 + h)) * 2048 + s) * 128 + d] = (bf16_t)val;
          else if (z == 1)
            Kh[(((size_t)(b * 8 + h)) * 2048 + s) * 128 + d] = (bf16_t)val;
          else
            Vt[(((size_t)(b * 8 + h)) * 128 + d) * 2048 + s] = (bf16_t)val;
        }
      }
    }
  }
}

// ---------------------------------------------------------------------------
// Flash attention v5: static-max softmax, one 64-row Q-tile per block.
// K/V fragments read DIRECTLY from global (L1/L2-resident; see header).
// No __syncthreads in the k-loop; only LDS is the per-wave P buffer.
// Ps row stride 88 (16B-aligned for b128 reads, 4-way write conflict
// instead of stride-80's 8-way).
// ---------------------------------------------------------------------------
__global__ __launch_bounds__(256, 4) void flash_k(const bf16_t* Qh,
                                                  const bf16_t* Kh,
                                                  const bf16_t* Vt, bf16_t* ctx,
                                                  const int* causal_p) {
  __shared__ bf16_t Pbuf[4 * 16 * 88];
  const int tid = threadIdx.x, w = tid >> 6, lane = tid & 63;
  const int q4 = lane >> 4, lo = lane & 15;
  const int n0 = blockIdx.x;
  const int u = n0 & 255, hi = n0 >> 8;
  const int bh = u & 15, p0 = u >> 4;
  const int t = hi ? (31 - p0) : p0;
  const int causal = *causal_p;
  const int kmax = causal ? t : 31;

  bf16_t* Ps = Pbuf + w * (16 * 88);

  // Q fragment: rows w*16+lo of this block's 64-row Q tile, all 128 dh.
  bf16x8 aq[4];
  {
    const bf16_t* qa = Qh + ((size_t)bh * 2048 + t * 64 + w * 16 + lo) * 128;
#pragma unroll
    for (int ks = 0; ks < 4; ks++) aq[ks] = *(const bf16x8*)(qa + ks * 32 + q4 * 8);
  }

  // Per-lane global fragment bases.
  // K (QK^T B-operand): row key = kt*64 + nt*16 + lo, dh chunk ks*32 + q4*8.
  const bf16_t* Kb = Kh + ((size_t)bh * 2048 + lo) * 128 + q4 * 8;
  // V (PV B-operand, Vt is [B,H,DH,S]): row d = n*16 + lo, keys kt*64 + q4*8 (+32).
  const bf16_t* Vb = Vt + ((size_t)bh * 128 + lo) * 2048 + q4 * 8;

  f32x4 acc[8], lacc;
#pragma unroll
  for (int i = 0; i < 8; i++) acc[i] = (f32x4){0.f, 0.f, 0.f, 0.f};
  lacc = (f32x4){0.f, 0.f, 0.f, 0.f};

  const bf16_t one = (bf16_t)1.0f;
  const bf16x8 vone = {one, one, one, one, one, one, one, one};
  const float sc2 = 0.08838834764831845f * 1.44269504088896f;

  for (int kt = 0; kt <= kmax; ++kt) {
    // ---- QK^T: S-tile [16 qrows x 64 keys] per wave ----
    const bf16_t* Kt = Kb + (size_t)kt * 64 * 128;
    f32x4 sa[4];
#pragma unroll
    for (int nt = 0; nt < 4; nt++) sa[nt] = (f32x4){0.f, 0.f, 0.f, 0.f};
#pragma unroll
    for (int ks = 0; ks < 4; ks++) {
#pragma unroll
      for (int nt = 0; nt < 4; nt++) {
        bf16x8 bk = *(const bf16x8*)(Kt + nt * (16 * 128) + ks * 32);
        sa[nt] = MFMA16(aq[ks], bk, sa[nt]);
      }
    }

    // ---- softmax numerator -> per-wave LDS P buffer ----
    const bool diag = causal && (kt == t);
    const int rloc = w * 16 + q4 * 4;
#pragma unroll
    for (int nt = 0; nt < 4; nt++) {
      int key = nt * 16 + lo;
#pragma unroll
      for (int rg = 0; rg < 4; rg++) {
        float pv = exp2f(sa[nt][rg] * sc2);
        if (diag && key > rloc + rg) pv = 0.f;
        Ps[(q4 * 4 + rg) * 88 + key] = (bf16_t)pv;
      }
    }

    // ---- P fragments (A-operand), row-sum, PV ----
    bf16x8 ap0 = *(const bf16x8*)&Ps[lo * 88 + q4 * 8];
    bf16x8 ap1 = *(const bf16x8*)&Ps[lo * 88 + 32 + q4 * 8];
    lacc = MFMA16(ap0, vone, lacc);
    lacc = MFMA16(ap1, vone, lacc);

    const bf16_t* Vtt = Vb + kt * 64;
#pragma unroll
    for (int n = 0; n < 8; n++) {
      bf16x8 bv0 = *(const bf16x8*)(Vtt + (size_t)n * (16 * 2048));
      bf16x8 bv1 = *(const bf16x8*)(Vtt + (size_t)n * (16 * 2048) + 32);
      acc[n] = MFMA16(ap0, bv0, acc[n]);
      acc[n] = MFMA16(ap1, bv1, acc[n]);
    }
  }

  int b = bh >> 3, h = bh & 7;
#pragma unroll
  for (int rg = 0; rg < 4; rg++) {
    float inv = 1.f / lacc[rg];
    int r = b * 2048 + t * 64 + w * 16 + q4 * 4 + rg;
#pragma unroll
    for (int n = 0; n < 8; n++)
      ctx[(size_t)r * 1024 + h * 128 + n * 16 + lo] = (bf16_t)(acc[n][rg] * inv);
  }
}

// ---------------------------------------------------------------------------
extern "C" void kernel_launch(void* const* d_in, const int* in_sizes, int n_in,
                              void* d_out, int out_size, void* d_ws,
                              size_t ws_size, hipStream_t stream) {
  const float* q = (const float*)d_in[0];
  const float* k = (const float*)d_in[1];
  const float* v = (const float*)d_in[2];
  const float* Wq = (const float*)d_in[3];
  const float* bq = (const float*)d_in[4];
  const float* Wk = (const float*)d_in[5];
  const float* bk = (const float*)d_in[6];
  const float* Wv = (const float*)d_in[7];
  const float* bv = (const float*)d_in[8];
  const float* Wo = (const float*)d_in[9];
  const float* bo = (const float*)d_in[10];
  const int* isc = (const int*)d_in[11];

  char* ws = (char*)d_ws;
  bf16_t* Wt = (bf16_t*)ws;                     // 8MB: W^T bf16 x4
  bf16_t* qb = (bf16_t*)(ws + (8ull << 20));    // 8MB
  bf16_t* kb = (bf16_t*)(ws + (16ull << 20));   // 8MB
  bf16_t* vb = (bf16_t*)(ws + (24ull << 20));   // 8MB
  bf16_t* Qh = (bf16_t*)(ws + (32ull << 20));   // 8MB [B,H,S,DH]
  bf16_t* Kh = (bf16_t*)(ws + (40ull << 20));   // 8MB [B,H,S,DH]
  bf16_t* Vt = (bf16_t*)(ws + (48ull << 20));   // 8MB [B,H,DH,S]
  bf16_t* ctx = (bf16_t*)(ws + (8ull << 20));   // reuse qb

  prep<<<dim3(10240), 256, 0, stream>>>(q, k, v, qb, kb, vb, Wq, Wk, Wv, Wo, Wt);

  gemm_k<0><<<dim3(8, 32, 3), 256, 0, stream>>>(qb, kb, vb, Wt, bq, bk, bv, Qh,
                                                Kh, Vt, nullptr);

  flash_k<<<dim3(512), 256, 0, stream>>>(Qh, Kh, Vt, ctx, isc);

  gemm_k<1><<<dim3(8, 32), 256, 0, stream>>>(ctx, nullptr, nullptr, Wt, bo,
                                             nullptr, nullptr, nullptr, nullptr,
                                             nullptr, (float*)d_out);
}

// Round 2
// 245.979 us; speedup vs baseline: 1.5358x; 1.5358x over previous
//
#include <hip/hip_runtime.h>
#include <math.h>

// MultiHeadBigBirdAttention: B=2, S=2048, E=1024, H=8, DH=128
// Pipeline (bf16 MFMA 16x16x32):
//   1. prep: fused {q,k,v fp32->bf16} + {W* fp32 [K][N] -> bf16 W^T [N][K]}
//   2. gemm_k<0> (grid.z=3): projections -> Qh/Kh [B,H,S,DH], Vt [B,H,DH,S]
//   3. flash_k: static-max flash -> ctx bf16
//   4. gemm_k<1>: ctx @ Wo^T + bo -> d_out fp32
//
// MFMA layouts (verified learn_hip m89/m91/m120):
//   C/D: col = lane&15, row = (lane>>4)*4 + reg
//   A:   m   = lane&15, k   = (lane>>4)*8 + j
//   B:   n   = lane&15, k   = (lane>>4)*8 + j
//
// R10 (this round):
//   - flash_k: REVERT to R8 structure (register-staged K/V LDS pipeline,
//     54us proven). R9's direct-global fragments were latency-unhidden at
//     2 waves/SIMD (grid=512 caps occupancy; LDS was never the limiter).
//     Keep only the validated Ps stride 80->88 fix (R9: conflicts 5.4M->270K;
//     stride-160B reads were a 4-way bank conflict).
//   - gemm_k: staging converted to global_load_lds width=16 (m93->m97 step,
//     +67% there). Chunk-XOR swizzle moved to the per-lane GLOBAL source
//     address (m173 pattern); LDS dest stays linear in lane. One barrier per
//     K-step; next tile's loads are issued right after the barrier and fly
//     during compute (drain happens at the next barrier).

typedef __bf16 bf16_t;
typedef __bf16 bf16x8 __attribute__((ext_vector_type(8)));
typedef float f32x4 __attribute__((ext_vector_type(4)));

#define MFMA16(a, b, c) __builtin_amdgcn_mfma_f32_16x16x32_bf16(a, b, c, 0, 0, 0)

#define GLD16(gp, lp)                                                     \
  __builtin_amdgcn_global_load_lds(                                       \
      (const __attribute__((address_space(1))) void*)(gp),                \
      (__attribute__((address_space(3))) void*)(lp), 16, 0, 0)

// ---------------------------------------------------------------------------
// prep: blocks 0..6143 convert q/k/v fp32->bf16 (8 elems/thread);
//       blocks 6144..10239 transpose the 4 weight matrices to bf16 W^T.
// ---------------------------------------------------------------------------
__global__ __launch_bounds__(256) void prep(const float* q, const float* k,
                                            const float* v, bf16_t* qb,
                                            bf16_t* kb, bf16_t* vb,
                                            const float* W0, const float* W1,
                                            const float* W2, const float* W3,
                                            bf16_t* Wt) {
  const int bid = blockIdx.x, tid = threadIdx.x;
  if (bid < 6144) {
    const int z = bid >> 11, chunk = bid & 2047;
    const float* x = (z == 0) ? q : (z == 1) ? k : v;
    bf16_t* y = (z == 0) ? qb : (z == 1) ? kb : vb;
    size_t i = ((size_t)chunk * 256 + tid) * 8;
    float4 a = *(const float4*)(x + i);
    float4 b = *(const float4*)(x + i + 4);
    bf16x8 o = {(bf16_t)a.x, (bf16_t)a.y, (bf16_t)a.z, (bf16_t)a.w,
                (bf16_t)b.x, (bf16_t)b.y, (bf16_t)b.z, (bf16_t)b.w};
    *(bf16x8*)(y + i) = o;
  } else {
    __shared__ float t[32][33];
    const int b2 = bid - 6144;
    const int wz = b2 >> 10, t2 = b2 & 1023;
    const float* W = (wz == 0) ? W0 : (wz == 1) ? W1 : (wz == 2) ? W2 : W3;
    bf16_t* o = Wt + (size_t)wz * 1024 * 1024;
    const int n0 = (t2 & 31) * 32, k0 = (t2 >> 5) * 32;
    const int tx = tid & 31, ty = tid >> 5;
#pragma unroll
    for (int i = 0; i < 4; i++)
      t[ty + 8 * i][tx] = W[(size_t)(k0 + ty + 8 * i) * 1024 + n0 + tx];
    __syncthreads();
#pragma unroll
    for (int i = 0; i < 4; i++)
      o[(size_t)(n0 + ty + 8 * i) * 1024 + k0 + tx] = (bf16_t)t[tx][ty + 8 * i];
  }
}

// ---------------------------------------------------------------------------
// GEMM 128x128 tile, BK=64, LDS double-buffered, global_load_lds staging.
// LDS [128][64] per buffer; slot(r,s) holds global chunk s^(r&7) (R6-proven
// conflict-free fragment reads). global_load_lds writes lane L at
// lds_base + L*16, i.e. row base+L>>3, slot L&7 -> lane L's GLOBAL address
// is pre-swizzled to chunk (L&7)^(L>>3) of its row (r&7 == L>>3 since the
// per-call row base is a multiple of 8).
// Loop: barrier (drains tile k's loads) -> issue tile k+1 loads (async,
// fly during compute) -> compute tile k. Buffer re-stage safety: tile k+2
// targets buf k&1, issued after iter-(k+1)'s barrier, which globally orders
// it after all iter-k reads of that buffer.
// ---------------------------------------------------------------------------
template <int MODE>
__global__ __launch_bounds__(256) void gemm_k(
    const bf16_t* qb, const bf16_t* kb, const bf16_t* vb, const bf16_t* Wt,
    const float* b0, const float* b1, const float* b2, bf16_t* Qh, bf16_t* Kh,
    bf16_t* Vt, float* Of32) {
  __shared__ bf16_t As[2][128 * 64];
  __shared__ bf16_t Bs[2][128 * 64];
  const int tid = threadIdx.x, w = tid >> 6, lane = tid & 63;
  const int bm = blockIdx.y, bn = blockIdx.x;
  const int wr = w >> 1, wc = w & 1, q4 = lane >> 4, lo = lane & 15;
  const int z = (MODE == 0) ? blockIdx.z : 3;
  const bf16_t* A = (MODE == 1) ? qb : (z == 0) ? qb : (z == 1) ? kb : vb;
  const bf16_t* Bt = Wt + (size_t)z * 1024 * 1024;
  const float* bias = (MODE == 1) ? b0 : (z == 0) ? b0 : (z == 1) ? b1 : b2;

  f32x4 acc[4][4];
#pragma unroll
  for (int m = 0; m < 4; m++)
#pragma unroll
    for (int n = 0; n < 4; n++) acc[m][n] = (f32x4){0.f, 0.f, 0.f, 0.f};

  // Per-lane pre-swizzled global source (m173): row r = w*32 + (lane>>3)
  // (+ j*8 per call), chunk c = (lane&7) ^ (lane>>3).
  const int srow = w * 32 + (lane >> 3);
  const int schunk = (lane & 7) ^ (lane >> 3);
  const bf16_t* gA = A + (size_t)(bm * 128 + srow) * 1024 + schunk * 8;
  const bf16_t* gB = Bt + (size_t)(bn * 128 + srow) * 1024 + schunk * 8;
  const int ldsrow = w * 32;  // wave-uniform LDS base row (call j adds j*8)

  auto stage = [&](int buf, int k0) {
#pragma unroll
    for (int j = 0; j < 4; j++) {
      GLD16(gA + k0 + j * 8192, &As[buf][(ldsrow + j * 8) * 64]);
      GLD16(gB + k0 + j * 8192, &Bs[buf][(ldsrow + j * 8) * 64]);
    }
  };

  stage(0, 0);
  for (int k = 0; k < 16; k++) {
    const int cur = k & 1;
    __syncthreads();  // drains vmcnt: tile k now resident in buf cur
    if (k < 15) stage(cur ^ 1, (k + 1) * 64);  // async, flies during compute

#pragma unroll
    for (int kc = 0; kc < 2; kc++) {
      bf16x8 af[4], bfr[4];
#pragma unroll
      for (int m = 0; m < 4; m++) {
        int rr = wr * 64 + m * 16 + lo;
        af[m] = *(const bf16x8*)&As[cur][rr * 64 + (((kc * 4 + q4) ^ (rr & 7)) * 8)];
      }
#pragma unroll
      for (int n = 0; n < 4; n++) {
        int rr = wc * 64 + n * 16 + lo;
        bfr[n] = *(const bf16x8*)&Bs[cur][rr * 64 + (((kc * 4 + q4) ^ (rr & 7)) * 8)];
      }
#pragma unroll
      for (int m = 0; m < 4; m++)
#pragma unroll
        for (int n = 0; n < 4; n++)
          acc[m][n] = MFMA16(af[m], bfr[n], acc[m][n]);
    }
  }

#pragma unroll
  for (int m = 0; m < 4; m++) {
#pragma unroll
    for (int n = 0; n < 4; n++) {
      int rowg0 = bm * 128 + wr * 64 + m * 16 + q4 * 4;
      int colg = bn * 128 + wc * 64 + n * 16 + lo;
      float bv = bias[colg];
#pragma unroll
      for (int rg = 0; rg < 4; rg++) {
        float val = acc[m][n][rg] + bv;
        int row = rowg0 + rg;
        if (MODE == 1) {
          Of32[(size_t)row * 1024 + colg] = val;
        } else {
          int b = row >> 11, s = row & 2047;  // S=2048
          int h = colg >> 7, d = colg & 127;  // DH=128
          if (z == 0)
            Qh[(((size_t)(b * 8 + h)) * 2048 + s) * 128 + d] = (bf16_t)val;
          else if (z == 1)
            Kh[(((size_t)(b * 8 + h)) * 2048 + s) * 128 + d] = (bf16_t)val;
          else
            Vt[(((size_t)(b * 8 + h)) * 128 + d) * 2048 + s] = (bf16_t)val;
        }
      }
    }
  }
}

// ---------------------------------------------------------------------------
// Flash attention v4 (R8 revert): static-max flash, one 64-row Q-tile per
// block, register-staged K/V double-buffered LDS pipeline. Only change vs
// R8: Ps row stride 80 -> 88 (still 16B-aligned; reads drop 4-way -> 2-way
// bank aliasing, writes stay spread — R9 measured conflicts 5.4M -> 270K).
// ---------------------------------------------------------------------------
__global__ __launch_bounds__(256) void flash_k(const bf16_t* Qh,
                                               const bf16_t* Kh,
                                               const bf16_t* Vt, bf16_t* ctx,
                                               const int* causal_p) {
  __shared__ bf16_t sm[32768 + 4 * 1408];
  const int tid = threadIdx.x, w = tid >> 6, lane = tid & 63;
  const int q4 = lane >> 4, lo = lane & 15;
  const int n0 = blockIdx.x;
  const int u = n0 & 255, hi = n0 >> 8;
  const int bh = u & 15, p0 = u >> 4;
  const int t = hi ? (31 - p0) : p0;
  const int causal = *causal_p;
  const int kmax = causal ? t : 31;

  bf16_t* Ps = sm + 32768 + w * 1408;

  bf16x8 aq[4];
  {
    const bf16_t* qa = Qh + ((size_t)bh * 2048 + t * 64 + w * 16 + lo) * 128;
#pragma unroll
    for (int ks = 0; ks < 4; ks++) aq[ks] = *(const bf16x8*)(qa + ks * 32 + q4 * 8);
  }

  const bf16_t* Kbase = Kh + (size_t)bh * 2048 * 128;
  const bf16_t* Vbase = Vt + (size_t)bh * 128 * 2048;
  const int kr = tid >> 2, kc = (tid & 3) * 4;
  const int vd = tid >> 1, vc = (tid & 1) * 4;

  bf16x8 kreg[4], vreg[4];
  auto loadKV = [&](int kt) {
    const bf16_t* kp = Kbase + (size_t)(kt * 64 + kr) * 128;
    const bf16_t* vp = Vbase + (size_t)vd * 2048 + kt * 64;
#pragma unroll
    for (int i = 0; i < 4; i++) {
      kreg[i] = *(const bf16x8*)(kp + (kc + i) * 8);
      vreg[i] = *(const bf16x8*)(vp + (vc + i) * 8);
    }
  };

  f32x4 acc[8], lacc;
#pragma unroll
  for (int i = 0; i < 8; i++) acc[i] = (f32x4){0.f, 0.f, 0.f, 0.f};
  lacc = (f32x4){0.f, 0.f, 0.f, 0.f};

  const bf16_t one = (bf16_t)1.0f;
  const bf16x8 vone = {one, one, one, one, one, one, one, one};
  const float sc2 = 0.08838834764831845f * 1.44269504088896f;

  loadKV(0);
  for (int kt = 0; kt <= kmax; ++kt) {
    bf16_t* Kd = sm + (kt & 1) * 8192;
    bf16_t* Vd = sm + 16384 + (kt & 1) * 8192;
#pragma unroll
    for (int i = 0; i < 4; i++)
      *(bf16x8*)&Kd[kr * 128 + (((kc + i) ^ (kr & 7)) * 8)] = kreg[i];
#pragma unroll
    for (int i = 0; i < 4; i++)
      *(bf16x8*)&Vd[vd * 64 + (((vc + i) ^ ((vd >> 1) & 7)) * 8)] = vreg[i];
    if (kt < kmax) loadKV(kt + 1);
    __syncthreads();

    f32x4 sa[4];
#pragma unroll
    for (int nt = 0; nt < 4; nt++) sa[nt] = (f32x4){0.f, 0.f, 0.f, 0.f};
#pragma unroll
    for (int ks = 0; ks < 4; ks++) {
#pragma unroll
      for (int nt = 0; nt < 4; nt++) {
        int key = nt * 16 + lo;
        bf16x8 bk =
            *(const bf16x8*)&Kd[key * 128 + (((ks * 4 + q4) ^ (key & 7)) * 8)];
        sa[nt] = MFMA16(aq[ks], bk, sa[nt]);
      }
    }

    const bool diag = causal && (kt == t);
    const int rloc = w * 16 + q4 * 4;
#pragma unroll
    for (int nt = 0; nt < 4; nt++) {
      int key = nt * 16 + lo;
#pragma unroll
      for (int rg = 0; rg < 4; rg++) {
        float pv = exp2f(sa[nt][rg] * sc2);
        if (diag && key > rloc + rg) pv = 0.f;
        Ps[(q4 * 4 + rg) * 88 + key] = (bf16_t)pv;
      }
    }

    bf16x8 ap0 = *(const bf16x8*)&Ps[lo * 88 + q4 * 8];
    bf16x8 ap1 = *(const bf16x8*)&Ps[lo * 88 + 32 + q4 * 8];
    lacc = MFMA16(ap0, vone, lacc);
    lacc = MFMA16(ap1, vone, lacc);
#pragma unroll
    for (int n = 0; n < 8; n++) {
      int d = n * 16 + lo;
      int sw = (d >> 1) & 7;
      bf16x8 bv0 = *(const bf16x8*)&Vd[d * 64 + ((q4 ^ sw) * 8)];
      bf16x8 bv1 = *(const bf16x8*)&Vd[d * 64 + (((4 + q4) ^ sw) * 8)];
      acc[n] = MFMA16(ap0, bv0, acc[n]);
      acc[n] = MFMA16(ap1, bv1, acc[n]);
    }
  }

  int b = bh >> 3, h = bh & 7;
#pragma unroll
  for (int rg = 0; rg < 4; rg++) {
    float inv = 1.f / lacc[rg];
    int r = b * 2048 + t * 64 + w * 16 + q4 * 4 + rg;
#pragma unroll
    for (int n = 0; n < 8; n++)
      ctx[(size_t)r * 1024 + h * 128 + n * 16 + lo] = (bf16_t)(acc[n][rg] * inv);
  }
}

// ---------------------------------------------------------------------------
extern "C" void kernel_launch(void* const* d_in, const int* in_sizes, int n_in,
                              void* d_out, int out_size, void* d_ws,
                              size_t ws_size, hipStream_t stream) {
  const float* q = (const float*)d_in[0];
  const float* k = (const float*)d_in[1];
  const float* v = (const float*)d_in[2];
  const float* Wq = (const float*)d_in[3];
  const float* bq = (const float*)d_in[4];
  const float* Wk = (const float*)d_in[5];
  const float* bk = (const float*)d_in[6];
  const float* Wv = (const float*)d_in[7];
  const float* bv = (const float*)d_in[8];
  const float* Wo = (const float*)d_in[9];
  const float* bo = (const float*)d_in[10];
  const int* isc = (const int*)d_in[11];

  char* ws = (char*)d_ws;
  bf16_t* Wt = (bf16_t*)ws;                     // 8MB: W^T bf16 x4
  bf16_t* qb = (bf16_t*)(ws + (8ull << 20));    // 8MB
  bf16_t* kb = (bf16_t*)(ws + (16ull << 20));   // 8MB
  bf16_t* vb = (bf16_t*)(ws + (24ull << 20));   // 8MB
  bf16_t* Qh = (bf16_t*)(ws + (32ull << 20));   // 8MB [B,H,S,DH]
  bf16_t* Kh = (bf16_t*)(ws + (40ull << 20));   // 8MB [B,H,S,DH]
  bf16_t* Vt = (bf16_t*)(ws + (48ull << 20));   // 8MB [B,H,DH,S]
  bf16_t* ctx = (bf16_t*)(ws + (8ull << 20));   // reuse qb

  prep<<<dim3(10240), 256, 0, stream>>>(q, k, v, qb, kb, vb, Wq, Wk, Wv, Wo, Wt);

  gemm_k<0><<<dim3(8, 32, 3), 256, 0, stream>>>(qb, kb, vb, Wt, bq, bk, bv, Qh,
                                                Kh, Vt, nullptr);

  flash_k<<<dim3(512), 256, 0, stream>>>(Qh, Kh, Vt, ctx, isc);

  gemm_k<1><<<dim3(8, 32), 256, 0, stream>>>(ctx, nullptr, nullptr, Wt, bo,
                                             nullptr, nullptr, nullptr, nullptr,
                                             nullptr, (float*)d_out);
}

// Round 3
// 228.857 us; speedup vs baseline: 1.6507x; 1.0748x over previous
//
#include <hip/hip_runtime.h>
#include <math.h>

// MultiHeadBigBirdAttention: B=2, S=2048, E=1024, H=8, DH=128
// Pipeline (bf16 MFMA 16x16x32):
//   1. prep: fused {q,k,v fp32->bf16} + {W* fp32 [K][N] -> bf16 W^T [N][K]}
//   2. gemm_k<0> (grid 32x8x3): projections -> Qh/Kh [B,H,S,DH], Vt [B,H,DH,S]
//   3. flash_k: static-max flash -> ctx bf16
//   4. gemm_k<1>: ctx @ Wo^T + bo -> d_out fp32
//
// MFMA layouts (verified learn_hip m89/m91/m120):
//   C/D: col = lane&15, row = (lane>>4)*4 + reg
//   A:   m   = lane&15, k   = (lane>>4)*8 + j
//   B:   n   = lane&15, k   = (lane>>4)*8 + j
//
// R11 (this round):
//   - gemm_k staging REVERTED to R8 register-staged pipeline (GLD16 2-phase
//     regressed 54->61us: barrier's vmcnt(0) drained the staging queue every
//     K-step; the reg-staged form is a T14 issue-early/write-late split whose
//     loads get a full iteration of slack and whose barrier drains nothing).
//   - XCD swizzle via grid-axis swap: grid (bm=32, bn=8, z); XCD = bm%8, so
//     each XCD's working set is 4 A-tiles (1MB) + full W^T (2MB) = 3MB < 4MB
//     L2. Old mapping had XCD = bn -> every XCD streamed all of A (R10:
//     FETCH 101MB vs ~30MB compulsory).
//   - flash_k: R8 structure + validated Ps stride 88 (R9: conflicts 5.4M->270K).

typedef __bf16 bf16_t;
typedef __bf16 bf16x8 __attribute__((ext_vector_type(8)));
typedef float f32x4 __attribute__((ext_vector_type(4)));

#define MFMA16(a, b, c) __builtin_amdgcn_mfma_f32_16x16x32_bf16(a, b, c, 0, 0, 0)

// ---------------------------------------------------------------------------
// prep: blocks 0..6143 convert q/k/v fp32->bf16 (8 elems/thread);
//       blocks 6144..10239 transpose the 4 weight matrices to bf16 W^T.
// ---------------------------------------------------------------------------
__global__ __launch_bounds__(256) void prep(const float* q, const float* k,
                                            const float* v, bf16_t* qb,
                                            bf16_t* kb, bf16_t* vb,
                                            const float* W0, const float* W1,
                                            const float* W2, const float* W3,
                                            bf16_t* Wt) {
  const int bid = blockIdx.x, tid = threadIdx.x;
  if (bid < 6144) {
    const int z = bid >> 11, chunk = bid & 2047;
    const float* x = (z == 0) ? q : (z == 1) ? k : v;
    bf16_t* y = (z == 0) ? qb : (z == 1) ? kb : vb;
    size_t i = ((size_t)chunk * 256 + tid) * 8;
    float4 a = *(const float4*)(x + i);
    float4 b = *(const float4*)(x + i + 4);
    bf16x8 o = {(bf16_t)a.x, (bf16_t)a.y, (bf16_t)a.z, (bf16_t)a.w,
                (bf16_t)b.x, (bf16_t)b.y, (bf16_t)b.z, (bf16_t)b.w};
    *(bf16x8*)(y + i) = o;
  } else {
    __shared__ float t[32][33];
    const int b2 = bid - 6144;
    const int wz = b2 >> 10, t2 = b2 & 1023;
    const float* W = (wz == 0) ? W0 : (wz == 1) ? W1 : (wz == 2) ? W2 : W3;
    bf16_t* o = Wt + (size_t)wz * 1024 * 1024;
    const int n0 = (t2 & 31) * 32, k0 = (t2 >> 5) * 32;
    const int tx = tid & 31, ty = tid >> 5;
#pragma unroll
    for (int i = 0; i < 4; i++)
      t[ty + 8 * i][tx] = W[(size_t)(k0 + ty + 8 * i) * 1024 + n0 + tx];
    __syncthreads();
#pragma unroll
    for (int i = 0; i < 4; i++)
      o[(size_t)(n0 + ty + 8 * i) * 1024 + k0 + tx] = (bf16_t)t[tx][ty + 8 * i];
  }
}

// ---------------------------------------------------------------------------
// GEMM 128x128 tile, BK=64, LDS double-buffered, register-staged pipeline
// (R8 skeleton, proven). tile k+1 is loaded global->VGPR at iter k, deposited
// to LDS dbuf at iter k+1 top. The barrier never drains VMEM (loads target
// private VGPRs); the loads' wait point is the next deposit, one full
// iteration later. Chunk-XOR swizzle = 0 LDS conflicts (R6-measured).
// Grid mapping: bm = blockIdx.x (32), bn = blockIdx.y (8) -> XCD = bm%8.
// ---------------------------------------------------------------------------
template <int MODE>
__global__ __launch_bounds__(256) void gemm_k(
    const bf16_t* qb, const bf16_t* kb, const bf16_t* vb, const bf16_t* Wt,
    const float* b0, const float* b1, const float* b2, bf16_t* Qh, bf16_t* Kh,
    bf16_t* Vt, float* Of32) {
  __shared__ bf16_t As[2][128 * 64];
  __shared__ bf16_t Bs[2][128 * 64];
  const int tid = threadIdx.x, w = tid >> 6, lane = tid & 63;
  const int bm = blockIdx.x, bn = blockIdx.y;  // swapped: XCD = bm%8
  const int wr = w >> 1, wc = w & 1, q4 = lane >> 4, lo = lane & 15;
  const int z = (MODE == 0) ? blockIdx.z : 3;
  const bf16_t* A = (MODE == 1) ? qb : (z == 0) ? qb : (z == 1) ? kb : vb;
  const bf16_t* Bt = Wt + (size_t)z * 1024 * 1024;
  const float* bias = (MODE == 1) ? b0 : (z == 0) ? b0 : (z == 1) ? b1 : b2;

  f32x4 acc[4][4];
#pragma unroll
  for (int m = 0; m < 4; m++)
#pragma unroll
    for (int n = 0; n < 4; n++) acc[m][n] = (f32x4){0.f, 0.f, 0.f, 0.f};

  const int r2 = tid >> 1;         // 0..127
  const int cb = (tid & 1) * 4;    // chunk base 0 / 4
  const bf16_t* Arow = A + (size_t)(bm * 128 + r2) * 1024;
  const bf16_t* Brow = Bt + (size_t)(bn * 128 + r2) * 1024;

  bf16x8 ar[4], br[4];
  auto loadAB = [&](int k0) {
#pragma unroll
    for (int i = 0; i < 4; i++) {
      ar[i] = *(const bf16x8*)(Arow + k0 + (cb + i) * 8);
      br[i] = *(const bf16x8*)(Brow + k0 + (cb + i) * 8);
    }
  };

  loadAB(0);
  for (int k = 0; k < 16; k++) {
    const int cur = k & 1;
    // deposit tile k (waits only on its own global loads)
#pragma unroll
    for (int i = 0; i < 4; i++) {
      *(bf16x8*)&As[cur][r2 * 64 + (((cb + i) ^ (r2 & 7)) * 8)] = ar[i];
      *(bf16x8*)&Bs[cur][r2 * 64 + (((cb + i) ^ (r2 & 7)) * 8)] = br[i];
    }
    // prefetch tile k+1 into private regs (in flight through barrier+compute)
    if (k < 15) loadAB((k + 1) * 64);
    __syncthreads();

#pragma unroll
    for (int kc = 0; kc < 2; kc++) {
      bf16x8 af[4], bfr[4];
#pragma unroll
      for (int m = 0; m < 4; m++) {
        int rr = wr * 64 + m * 16 + lo;
        af[m] = *(const bf16x8*)&As[cur][rr * 64 + (((kc * 4 + q4) ^ (rr & 7)) * 8)];
      }
#pragma unroll
      for (int n = 0; n < 4; n++) {
        int rr = wc * 64 + n * 16 + lo;
        bfr[n] = *(const bf16x8*)&Bs[cur][rr * 64 + (((kc * 4 + q4) ^ (rr & 7)) * 8)];
      }
#pragma unroll
      for (int m = 0; m < 4; m++)
#pragma unroll
        for (int n = 0; n < 4; n++)
          acc[m][n] = MFMA16(af[m], bfr[n], acc[m][n]);
    }
    // no trailing barrier: dbuf + top-of-iter deposit make it safe
  }

#pragma unroll
  for (int m = 0; m < 4; m++) {
#pragma unroll
    for (int n = 0; n < 4; n++) {
      int rowg0 = bm * 128 + wr * 64 + m * 16 + q4 * 4;
      int colg = bn * 128 + wc * 64 + n * 16 + lo;
      float bv = bias[colg];
#pragma unroll
      for (int rg = 0; rg < 4; rg++) {
        float val = acc[m][n][rg] + bv;
        int row = rowg0 + rg;
        if (MODE == 1) {
          Of32[(size_t)row * 1024 + colg] = val;
        } else {
          int b = row >> 11, s = row & 2047;  // S=2048
          int h = colg >> 7, d = colg & 127;  // DH=128
          if (z == 0)
            Qh[(((size_t)(b * 8 + h)) * 2048 + s) * 128 + d] = (bf16_t)val;
          else if (z == 1)
            Kh[(((size_t)(b * 8 + h)) * 2048 + s) * 128 + d] = (bf16_t)val;
          else
            Vt[(((size_t)(b * 8 + h)) * 128 + d) * 2048 + s] = (bf16_t)val;
        }
      }
    }
  }
}

// ---------------------------------------------------------------------------
// Flash attention v4 (R8 structure): static-max flash, one 64-row Q-tile per
// block, register-staged K/V double-buffered LDS pipeline. Ps row stride 88
// (16B-aligned; R9 measured conflicts 5.4M -> 270K vs stride 80).
// ---------------------------------------------------------------------------
__global__ __launch_bounds__(256) void flash_k(const bf16_t* Qh,
                                               const bf16_t* Kh,
                                               const bf16_t* Vt, bf16_t* ctx,
                                               const int* causal_p) {
  __shared__ bf16_t sm[32768 + 4 * 1408];
  const int tid = threadIdx.x, w = tid >> 6, lane = tid & 63;
  const int q4 = lane >> 4, lo = lane & 15;
  const int n0 = blockIdx.x;
  const int u = n0 & 255, hi = n0 >> 8;
  const int bh = u & 15, p0 = u >> 4;
  const int t = hi ? (31 - p0) : p0;
  const int causal = *causal_p;
  const int kmax = causal ? t : 31;

  bf16_t* Ps = sm + 32768 + w * 1408;

  bf16x8 aq[4];
  {
    const bf16_t* qa = Qh + ((size_t)bh * 2048 + t * 64 + w * 16 + lo) * 128;
#pragma unroll
    for (int ks = 0; ks < 4; ks++) aq[ks] = *(const bf16x8*)(qa + ks * 32 + q4 * 8);
  }

  const bf16_t* Kbase = Kh + (size_t)bh * 2048 * 128;
  const bf16_t* Vbase = Vt + (size_t)bh * 128 * 2048;
  const int kr = tid >> 2, kc = (tid & 3) * 4;
  const int vd = tid >> 1, vc = (tid & 1) * 4;

  bf16x8 kreg[4], vreg[4];
  auto loadKV = [&](int kt) {
    const bf16_t* kp = Kbase + (size_t)(kt * 64 + kr) * 128;
    const bf16_t* vp = Vbase + (size_t)vd * 2048 + kt * 64;
#pragma unroll
    for (int i = 0; i < 4; i++) {
      kreg[i] = *(const bf16x8*)(kp + (kc + i) * 8);
      vreg[i] = *(const bf16x8*)(vp + (vc + i) * 8);
    }
  };

  f32x4 acc[8], lacc;
#pragma unroll
  for (int i = 0; i < 8; i++) acc[i] = (f32x4){0.f, 0.f, 0.f, 0.f};
  lacc = (f32x4){0.f, 0.f, 0.f, 0.f};

  const bf16_t one = (bf16_t)1.0f;
  const bf16x8 vone = {one, one, one, one, one, one, one, one};
  const float sc2 = 0.08838834764831845f * 1.44269504088896f;

  loadKV(0);
  for (int kt = 0; kt <= kmax; ++kt) {
    bf16_t* Kd = sm + (kt & 1) * 8192;
    bf16_t* Vd = sm + 16384 + (kt & 1) * 8192;
#pragma unroll
    for (int i = 0; i < 4; i++)
      *(bf16x8*)&Kd[kr * 128 + (((kc + i) ^ (kr & 7)) * 8)] = kreg[i];
#pragma unroll
    for (int i = 0; i < 4; i++)
      *(bf16x8*)&Vd[vd * 64 + (((vc + i) ^ ((vd >> 1) & 7)) * 8)] = vreg[i];
    if (kt < kmax) loadKV(kt + 1);
    __syncthreads();

    f32x4 sa[4];
#pragma unroll
    for (int nt = 0; nt < 4; nt++) sa[nt] = (f32x4){0.f, 0.f, 0.f, 0.f};
#pragma unroll
    for (int ks = 0; ks < 4; ks++) {
#pragma unroll
      for (int nt = 0; nt < 4; nt++) {
        int key = nt * 16 + lo;
        bf16x8 bk =
            *(const bf16x8*)&Kd[key * 128 + (((ks * 4 + q4) ^ (key & 7)) * 8)];
        sa[nt] = MFMA16(aq[ks], bk, sa[nt]);
      }
    }

    const bool diag = causal && (kt == t);
    const int rloc = w * 16 + q4 * 4;
#pragma unroll
    for (int nt = 0; nt < 4; nt++) {
      int key = nt * 16 + lo;
#pragma unroll
      for (int rg = 0; rg < 4; rg++) {
        float pv = exp2f(sa[nt][rg] * sc2);
        if (diag && key > rloc + rg) pv = 0.f;
        Ps[(q4 * 4 + rg) * 88 + key] = (bf16_t)pv;
      }
    }

    bf16x8 ap0 = *(const bf16x8*)&Ps[lo * 88 + q4 * 8];
    bf16x8 ap1 = *(const bf16x8*)&Ps[lo * 88 + 32 + q4 * 8];
    lacc = MFMA16(ap0, vone, lacc);
    lacc = MFMA16(ap1, vone, lacc);
#pragma unroll
    for (int n = 0; n < 8; n++) {
      int d = n * 16 + lo;
      int sw = (d >> 1) & 7;
      bf16x8 bv0 = *(const bf16x8*)&Vd[d * 64 + ((q4 ^ sw) * 8)];
      bf16x8 bv1 = *(const bf16x8*)&Vd[d * 64 + (((4 + q4) ^ sw) * 8)];
      acc[n] = MFMA16(ap0, bv0, acc[n]);
      acc[n] = MFMA16(ap1, bv1, acc[n]);
    }
  }

  int b = bh >> 3, h = bh & 7;
#pragma unroll
  for (int rg = 0; rg < 4; rg++) {
    float inv = 1.f / lacc[rg];
    int r = b * 2048 + t * 64 + w * 16 + q4 * 4 + rg;
#pragma unroll
    for (int n = 0; n < 8; n++)
      ctx[(size_t)r * 1024 + h * 128 + n * 16 + lo] = (bf16_t)(acc[n][rg] * inv);
  }
}

// ---------------------------------------------------------------------------
extern "C" void kernel_launch(void* const* d_in, const int* in_sizes, int n_in,
                              void* d_out, int out_size, void* d_ws,
                              size_t ws_size, hipStream_t stream) {
  const float* q = (const float*)d_in[0];
  const float* k = (const float*)d_in[1];
  const float* v = (const float*)d_in[2];
  const float* Wq = (const float*)d_in[3];
  const float* bq = (const float*)d_in[4];
  const float* Wk = (const float*)d_in[5];
  const float* bk = (const float*)d_in[6];
  const float* Wv = (const float*)d_in[7];
  const float* bv = (const float*)d_in[8];
  const float* Wo = (const float*)d_in[9];
  const float* bo = (const float*)d_in[10];
  const int* isc = (const int*)d_in[11];

  char* ws = (char*)d_ws;
  bf16_t* Wt = (bf16_t*)ws;                     // 8MB: W^T bf16 x4
  bf16_t* qb = (bf16_t*)(ws + (8ull << 20));    // 8MB
  bf16_t* kb = (bf16_t*)(ws + (16ull << 20));   // 8MB
  bf16_t* vb = (bf16_t*)(ws + (24ull << 20));   // 8MB
  bf16_t* Qh = (bf16_t*)(ws + (32ull << 20));   // 8MB [B,H,S,DH]
  bf16_t* Kh = (bf16_t*)(ws + (40ull << 20));   // 8MB [B,H,S,DH]
  bf16_t* Vt = (bf16_t*)(ws + (48ull << 20));   // 8MB [B,H,DH,S]
  bf16_t* ctx = (bf16_t*)(ws + (8ull << 20));   // reuse qb

  prep<<<dim3(10240), 256, 0, stream>>>(q, k, v, qb, kb, vb, Wq, Wk, Wv, Wo, Wt);

  // grid swapped to (bm=32, bn=8, z): XCD = bm%8 -> per-XCD L2 working set
  // = 4 A-tiles (1MB) + W^T (2MB) = 3MB < 4MB.
  gemm_k<0><<<dim3(32, 8, 3), 256, 0, stream>>>(qb, kb, vb, Wt, bq, bk, bv, Qh,
                                                Kh, Vt, nullptr);

  flash_k<<<dim3(512), 256, 0, stream>>>(Qh, Kh, Vt, ctx, isc);

  gemm_k<1><<<dim3(32, 8), 256, 0, stream>>>(ctx, nullptr, nullptr, Wt, bo,
                                             nullptr, nullptr, nullptr, nullptr,
                                             nullptr, (float*)d_out);
}